// Round 19
// baseline (676.633 us; speedup 1.0000x reference)
//
#include <hip/hip_runtime.h>
#include <cstdint>
#include <cstddef>

#define NLAYERS 19
#define NB 4
#define RES_C 128
#define DIL2 256
#define SKIPC 256
#define INC 60
#define CONDC 80
#define OUTC 240
#define T_IN 6144
#define T0LEN 6135   // after start conv (K=10, VALID)
#define T_FIN 4601
#define TILE 64      // start/skipsum/end tile
#define LTILE 16     // layer tile (R19: t-major rows stay 256B -> safe to shrink)
#define BLK 512
#define ZROWS 4608   // window rows per (layer,batch)
#define XB_T 6208    // xb mirror rows (T_IN + pad for tap1 overread)
#define NSPLIT 4
#define LPG 5        // layers per split group (last group has 4)

#define NDIL (NLAYERS*256*256)
#define NSKP (NLAYERS*256*128)
#define NRES (NLAYERS*128*128)
#define NEND (256*256)
#define NSTART (10*128*64)

typedef short bf16x8 __attribute__((ext_vector_type(8)));
typedef float f32x4 __attribute__((ext_vector_type(4)));
typedef unsigned uint32x2 __attribute__((ext_vector_type(2)));

#if __has_builtin(__builtin_amdgcn_exp2f)
#define EXP2F(x) __builtin_amdgcn_exp2f(x)
#else
#define EXP2F(x) exp2f(x)
#endif
#if __has_builtin(__builtin_amdgcn_rcpf)
#define RCPF(x) __builtin_amdgcn_rcpf(x)
#else
#define RCPF(x) (1.0f/(x))
#endif

__device__ __forceinline__ float fexp(float x){ return EXP2F(x * 1.4426950408889634f); }
__device__ __forceinline__ float fsigmoid(float x){ return RCPF(1.0f + fexp(-x)); }
__device__ __forceinline__ float ftanh(float x){ return 1.0f - 2.0f * RCPF(1.0f + fexp(2.0f*x)); }

__device__ __forceinline__ unsigned short f2bf(float f){
  unsigned u = __builtin_bit_cast(unsigned, f);
  u = u + 0x7FFFu + ((u >> 16) & 1u);   // RNE (finite values only)
  return (unsigned short)(u >> 16);
}
__device__ __forceinline__ float bf2f(unsigned short h){
  unsigned u = ((unsigned)h) << 16;
  return __builtin_bit_cast(float, u);
}

// async 16B global->LDS DMA; LDS dest = base + lane*16 (wave-uniform base), global src per-lane
__device__ __forceinline__ void gl_lds16(const void* g, void* l){
  __builtin_amdgcn_global_load_lds((const __attribute__((address_space(1))) unsigned int*)g,
                                   (__attribute__((address_space(3))) unsigned int*)l, 16, 0, 0);
}

// ---------------------------------------------------------------------------
// Pack weights to bf16 (R5-proven).
__global__ void prep_weights(const float* __restrict__ dil_w, const float* __restrict__ skip_w,
                             const float* __restrict__ res_w, const float* __restrict__ end_w,
                             const float* __restrict__ start_w,
                             unsigned short* __restrict__ dilWb, unsigned short* __restrict__ skipWb,
                             unsigned short* __restrict__ resWb, unsigned short* __restrict__ endWb,
                             unsigned short* __restrict__ startWb){
  const int total = NDIL + NSKP + NRES + NEND + NSTART;
  for (int idx = blockIdx.x*256 + threadIdx.x; idx < total; idx += gridDim.x*256){
    if (idx < NDIL){
      int l = idx >> 16; int rem = idx & 65535; int m = rem >> 8; int k = rem & 255;
      int o = ((m & 1) << 7) + (m >> 1); int c = k & 127; int tap = k >> 7;
      dilWb[idx] = f2bf(dil_w[(((size_t)l*256 + o)*128 + c)*2 + tap]);
    } else if (idx < NDIL + NSKP){
      int j = idx - NDIL;
      skipWb[j] = f2bf(skip_w[j]);
    } else if (idx < NDIL + NSKP + NRES){
      int j = idx - NDIL - NSKP;
      resWb[j] = f2bf(res_w[j]);
    } else if (idx < NDIL + NSKP + NRES + NEND){
      int j = idx - NDIL - NSKP - NRES;
      int m = j >> 8; int k = j & 255;
      endWb[j] = (m < OUTC) ? f2bf(end_w[(size_t)m*256 + k]) : 0;
    } else {
      int j = idx - NDIL - NSKP - NRES - NEND;
      int k = j >> 13; int rem = j & 8191; int oc = rem >> 6; int c = rem & 63;
      startWb[j] = (c < INC) ? f2bf(start_w[((size_t)oc*INC + c)*10 + k]) : 0;
    }
  }
}

// ---------------------------------------------------------------------------
__global__ void prep_bias(const float* __restrict__ cond, const float* __restrict__ dil_b,
                          const float* __restrict__ cond_w, const float* __restrict__ cond_b,
                          const float* __restrict__ cend_w, const float* __restrict__ cend_b,
                          const float* __restrict__ skip_b,
                          float* __restrict__ cbias, float* __restrict__ sbc){
  int blk = blockIdx.x; int m = threadIdx.x;
  if (blk < NLAYERS*NB){
    int l = blk >> 2, b = blk & 3;
    int o = ((m & 1) << 7) + (m >> 1);
    float acc = dil_b[l*256 + o] + cond_b[l*256 + o];
    const float* w = cond_w + ((size_t)l*256 + o)*CONDC;
    const float* cv = cond + b*CONDC;
    for (int c = 0; c < CONDC; ++c) acc += w[c]*cv[c];
    cbias[((size_t)l*NB + b)*256 + m] = acc;
  } else {
    int b = blk - NLAYERS*NB;
    float acc = cend_b[m];
    const float* w = cend_w + (size_t)m*CONDC;
    const float* cv = cond + b*CONDC;
    for (int c = 0; c < CONDC; ++c) acc += w[c]*cv[c];
    for (int l = 0; l < NLAYERS; ++l) acc += skip_b[l*256 + m];
    sbc[b*256 + m] = acc;
  }
}

// ---------------------------------------------------------------------------
// start conv via MFMA (R5-proven), writes bf16 x-mirror only
__global__ __launch_bounds__(BLK) void start_mfma(const float* __restrict__ in,
    const unsigned short* __restrict__ startWb, const float* __restrict__ bias,
    unsigned short* __restrict__ xb){
  __shared__ char Bs[80*128];   // [tt:80][c:64] bf16, slot ^= (tt&7)
  const int tid = threadIdx.x;
  const int b = blockIdx.y; const int t0 = blockIdx.x * TILE;
  const int lane = tid & 63;
  const int wave = __builtin_amdgcn_readfirstlane(tid >> 6);
  const int q = lane >> 4, r16 = lane & 15;

  #pragma unroll
  for (int i = 0; i < 5; ++i){
    int j = tid + i*BLK;              // 0..2559 = 32 c-pairs x 80 tt
    int c2 = j / 80, tt = j % 80;
    int c = 2*c2; int gt = t0 + tt;
    float v0 = 0.f, v1 = 0.f;
    if (gt < T_IN && c < INC){
      const float* base = in + ((size_t)(b*INC + c))*T_IN + gt;
      v0 = base[0]; v1 = base[T_IN];
    }
    unsigned u = (unsigned)f2bf(v0) | ((unsigned)f2bf(v1) << 16);
    int slot = c2 >> 2;
    *(unsigned*)(Bs + tt*128 + ((((slot ^ (tt & 7)) << 4)) | ((4*c2) & 15))) = u;
  }
  __syncthreads();

  f32x4 acc[4] = {};
  for (int k = 0; k < 10; ++k){
    const unsigned short* A = startWb + ((size_t)k*128 + wave*16)*64;
    #pragma unroll
    for (int kk = 0; kk < 2; ++kk){
      int k0 = kk*32 + q*8;
      bf16x8 a = *(const bf16x8*)(A + (size_t)r16*64 + k0);
      int slot = k0 >> 3;
      #pragma unroll
      for (int nt = 0; nt < 4; ++nt){
        int t = nt*16 + r16 + k;
        bf16x8 bf = *(const bf16x8*)(Bs + t*128 + ((slot ^ (t & 7)) << 4));
        acc[nt] = __builtin_amdgcn_mfma_f32_16x16x32_bf16(a, bf, acc[nt], 0, 0, 0);
      }
    }
  }
  const float* bb = bias + wave*16;
  #pragma unroll
  for (int nt = 0; nt < 4; ++nt){
    int gt = t0 + nt*16 + r16;
    if (gt < T0LEN){
      float v[4];
      #pragma unroll
      for (int rr = 0; rr < 4; ++rr) v[rr] = acc[nt][rr] + bb[4*q + rr];
      uint32x2 u;
      u.x = (unsigned)f2bf(v[0]) | ((unsigned)f2bf(v[1]) << 16);
      u.y = (unsigned)f2bf(v[2]) | ((unsigned)f2bf(v[3]) << 16);
      *(uint32x2*)(xb + ((size_t)b*XB_T + gt)*128 + wave*16 + 4*q) = u;
    }
  }
}

// ---------------------------------------------------------------------------
// Fused MFMA layer (R19, LTILE=16): bf16-only x stream. Stage via async
// global_load_lds (waves 0-3 tap0, 4-7 tap1); dil GEMM + gate -> Bz; z-flush
// (LDS bounce, 256B rows); res GEMM with residual from BxT1; xb via LDS bounce.
__global__ __launch_bounds__(BLK) void layer_mfma(
    const unsigned short* __restrict__ xbin, unsigned short* __restrict__ xbout,
    unsigned short* __restrict__ zl,      // zbuf + l*NB*ZROWS*128
    const unsigned short* __restrict__ dilWb, const unsigned short* __restrict__ resWb,
    const float* __restrict__ cbias, const float* __restrict__ res_b,
    int layer, int d, int Tin, int Tout, int woff, int last){
  __shared__ char BxT0[LTILE*256];  // tap0 x[t]   [t][128ch] bf16, src-swizzled ^(t&15)
  __shared__ char BxT1[LTILE*256];  // tap1 x[t+d]
  __shared__ char Bz[LTILE*256];    // z [t][128ch] bf16, slot ^= (t&15)
  const int tid = threadIdx.x;
  const int b = blockIdx.y; const int t0 = blockIdx.x*LTILE;
  const int lane = tid & 63;
  const int wave = __builtin_amdgcn_readfirstlane(tid >> 6);
  const int q = lane >> 4;
  const int r16 = lane & 15;

  // ---- async stage: 1 DMA per wave; waves 0-3 cover tap0, waves 4-7 tap1
  {
    int r = lane >> 4;               // 0..3
    int p = lane & 15;               // physical slot
    int row0 = (wave & 3)*4;         // wave-uniform
    int trow = row0 + r;
    int so = (p ^ (trow & 15)) * 8;  // source element offset within row
    const unsigned short* gb = xbin + (size_t)b*XB_T*128;
    if (wave < 4)
      gl_lds16(gb + (size_t)(t0 + trow)*128 + so,     BxT0 + row0*256);
    else
      gl_lds16(gb + (size_t)(t0 + trow + d)*128 + so, BxT1 + row0*256);
  }
  __syncthreads();   // drains DMA

  // ---- dilated GEMM: M=256 (f/g interleaved), K=256 (2 taps x 128), N=16.
  f32x4 acc[2] = {};
  #pragma unroll
  for (int tap = 0; tap < 2; ++tap){
    const char* Bt = tap ? BxT1 : BxT0;
    const unsigned short* A = dilWb + (size_t)layer*256*256 + (size_t)(wave*32)*256 + tap*128;
    for (int kk = 0; kk < 4; ++kk){
      int k0 = kk*32 + q*8;          // 0..127 within tap
      bf16x8 a0 = *(const bf16x8*)(A + (size_t)r16*256 + k0);
      bf16x8 a1 = *(const bf16x8*)(A + (size_t)(16 + r16)*256 + k0);
      int slot = k0 >> 3;
      bf16x8 bf = *(const bf16x8*)(Bt + r16*256 + ((slot ^ (r16 & 15)) << 4));
      acc[0] = __builtin_amdgcn_mfma_f32_16x16x32_bf16(a0, bf, acc[0], 0, 0, 0);
      acc[1] = __builtin_amdgcn_mfma_f32_16x16x32_bf16(a1, bf, acc[1], 0, 0, 0);
    }
  }

  // ---- gate + write z to Bz (rows 4q+r hold f,g,f,g of channels 2q,2q+1)
  {
    const float* cb = cbias + ((size_t)layer*NB + b)*256 + wave*32;
    #pragma unroll
    for (int mt = 0; mt < 2; ++mt){
      float bf0 = cb[mt*16 + 4*q + 0];
      float bg0 = cb[mt*16 + 4*q + 1];
      float bf1 = cb[mt*16 + 4*q + 2];
      float bg1 = cb[mt*16 + 4*q + 3];
      int ch0 = wave*16 + mt*8 + 2*q;
      int slot = ch0 >> 3;
      float z0 = ftanh(acc[mt][0] + bf0) * fsigmoid(acc[mt][1] + bg0);
      float z1 = ftanh(acc[mt][2] + bf1) * fsigmoid(acc[mt][3] + bg1);
      unsigned u = (unsigned)f2bf(z0) | ((unsigned)f2bf(z1) << 16);
      *(unsigned*)(Bz + r16*256 + ((slot ^ (r16 & 15)) << 4) + ((2*ch0) & 15)) = u;
    }
  }
  __syncthreads();

  // ---- z-flush: Bz -> zbuf[l][b][windex][128], coalesced rows (256B segments)
  {
    unsigned short* zgb = zl + (size_t)b*ZROWS*128;
    #pragma unroll
    for (int i = 0; i < 2; ++i){
      int j = tid + i*BLK;            // 16 rows x 64 u32
      int row = j >> 6, cu = j & 63;
      int gt = t0 + row;
      int windex = gt - woff;
      if (gt < Tout && windex >= 0){
        int slot = cu >> 2;
        unsigned u = *(const unsigned*)(Bz + row*256 + (((slot ^ (row & 15)) << 4) | ((4*cu) & 15)));
        *(unsigned*)(zgb + (size_t)windex*128 + 2*cu) = u;
      }
    }
  }

  // ---- res GEMM: M=128, K=128; residual from BxT1 (x[t+d] in LDS); bf16 out.
  if (!last){
    f32x4 racc = {};
    const unsigned short* A = resWb + (size_t)layer*128*128 + (size_t)(wave*16)*128;
    for (int kk = 0; kk < 4; ++kk){
      int k0 = kk*32 + q*8;
      bf16x8 a0 = *(const bf16x8*)(A + (size_t)r16*128 + k0);
      int slot = k0 >> 3;
      bf16x8 bf = *(const bf16x8*)(Bz + r16*256 + ((slot ^ (r16 & 15)) << 4));
      racc = __builtin_amdgcn_mfma_f32_16x16x32_bf16(a0, bf, racc, 0, 0, 0);
    }
    const float* rb = res_b + layer*RES_C + wave*16;
    {
      float v[4];
      #pragma unroll
      for (int rr = 0; rr < 4; ++rr){
        int m = wave*16 + 4*q + rr;
        // residual: x[t+d][m] from BxT1 (same swizzle as stage wrote)
        unsigned short xh = *(const unsigned short*)(BxT1 + r16*256 +
            ((((m >> 3) ^ (r16 & 15)) << 4) | ((2*m) & 15)));
        v[rr] = racc[rr] + rb[4*q + rr] + bf2f(xh);
      }
      // pack bf16 x to LDS (reuse BxT0) for coalesced mirror write
      uint32x2 u;
      u.x = (unsigned)f2bf(v[0]) | ((unsigned)f2bf(v[1]) << 16);
      u.y = (unsigned)f2bf(v[2]) | ((unsigned)f2bf(v[3]) << 16);
      int m0 = wave*16 + 4*q;
      int slot = m0 >> 3;
      *(uint32x2*)(BxT0 + r16*256 + (((slot ^ (r16 & 15)) << 4) | ((2*m0) & 15))) = u;
    }
    __syncthreads();
    // flush mirror rows coalesced
    unsigned short* xg = xbout + (size_t)b*XB_T*128;
    #pragma unroll
    for (int i = 0; i < 2; ++i){
      int j = tid + i*BLK;            // 16 rows x 64 u32
      int row = j >> 6, cu = j & 63;
      int gt = t0 + row;
      if (gt < Tout){
        int slot = cu >> 2;
        unsigned u = *(const unsigned*)(BxT0 + row*256 + (((slot ^ (row & 15)) << 4) | ((4*cu) & 15)));
        *(unsigned*)(xg + (size_t)gt*128 + 2*cu) = u;
      }
    }
  }
}

// ---------------------------------------------------------------------------
// pass1 (R17-proven): partial[g] = sum_{l in group g} skipW[l] @ z_l, bf16 out.
__global__ __launch_bounds__(BLK) void skipsum_mfma(
    const unsigned short* __restrict__ zbuf,
    const unsigned short* __restrict__ skipWb,
    unsigned short* __restrict__ partial){
  __shared__ char BzP[2][64*256];   // z tile double-buffer, slot ^= (row&15)
  const int tid = threadIdx.x;
  const int b = blockIdx.y; const int t0 = blockIdx.x*TILE;
  const int g = blockIdx.z;
  const int l0 = g*LPG;
  const int l1 = (l0 + LPG < NLAYERS) ? (l0 + LPG) : NLAYERS;
  const int lane = tid & 63;
  const int wave = __builtin_amdgcn_readfirstlane(tid >> 6);
  const int q = lane >> 4, r16 = lane & 15;

  auto stageZ = [&](int l, int buf){
    int r = lane >> 4, p = lane & 15;
    const unsigned short* zb = zbuf + ((size_t)l*NB + b)*ZROWS*128;
    #pragma unroll
    for (int h = 0; h < 2; ++h){
      int row0 = wave*8 + h*4;       // wave-uniform
      int trow = row0 + r;
      gl_lds16(zb + (size_t)(t0 + trow)*128 + (p ^ (trow & 15))*8,
               BzP[buf] + row0*256);
    }
  };

  stageZ(l0, l0 & 1);
  __syncthreads();

  f32x4 sacc[2][4] = {};
  for (int l = l0; l < l1; ++l){
    if (l + 1 < l1) stageZ(l + 1, (l + 1) & 1);
    const unsigned short* A = skipWb + ((size_t)l*256 + wave*32)*128;
    const char* Bb = BzP[l & 1];
    for (int kk = 0; kk < 4; ++kk){
      int k0 = kk*32 + q*8;
      bf16x8 a0 = *(const bf16x8*)(A + (size_t)r16*128 + k0);
      bf16x8 a1 = *(const bf16x8*)(A + (size_t)(16 + r16)*128 + k0);
      int slot = k0 >> 3;
      #pragma unroll
      for (int nt = 0; nt < 4; ++nt){
        int t = nt*16 + r16;
        bf16x8 bf = *(const bf16x8*)(Bb + t*256 + ((slot ^ (t & 15)) << 4));
        sacc[0][nt] = __builtin_amdgcn_mfma_f32_16x16x32_bf16(a0, bf, sacc[0][nt], 0, 0, 0);
        sacc[1][nt] = __builtin_amdgcn_mfma_f32_16x16x32_bf16(a1, bf, sacc[1][nt], 0, 0, 0);
      }
    }
    __syncthreads();
  }

  unsigned short* pg = partial + (size_t)g*NB*SKIPC*T_FIN;
  #pragma unroll
  for (int mt = 0; mt < 2; ++mt){
    #pragma unroll
    for (int nt = 0; nt < 4; ++nt){
      int gt = t0 + nt*16 + r16;
      if (gt < T_FIN){
        #pragma unroll
        for (int rr = 0; rr < 4; ++rr){
          int m = wave*32 + mt*16 + 4*q + rr;
          pg[((size_t)(b*SKIPC + m))*T_FIN + gt] = f2bf(sacc[mt][nt][rr]);
        }
      }
    }
  }
}

// ---------------------------------------------------------------------------
// pass2: out = sigmoid(end_b + endW @ tanh(sum_g partial[g] + sbc))
__global__ __launch_bounds__(BLK) void end_mfma(
    const unsigned short* __restrict__ partial, const unsigned short* __restrict__ endWb,
    const float* __restrict__ sbc, const float* __restrict__ end_b,
    float* __restrict__ out){
  __shared__ char Bs[64*512];   // [t][s:256] bf16, slot ^= (t&31)
  const int tid = threadIdx.x;
  const int b = blockIdx.y; const int t0 = blockIdx.x*TILE;
  const int lane = tid & 63;
  const int wave = __builtin_amdgcn_readfirstlane(tid >> 6);
  const int q = lane >> 4;
  const int r16 = lane & 15;
  const size_t gs = (size_t)NB*SKIPC*T_FIN;

  {
    const int t = lane;
    const int gt = t0 + t;
    #pragma unroll
    for (int i = 0; i < 32; i += 2){
      int s0 = wave*32 + i;
      float v0 = 0.f, v1 = 0.f;
      if (gt < T_FIN){
        size_t base = ((size_t)(b*SKIPC + s0))*T_FIN + gt;
        float a0 = bf2f(partial[base])        + bf2f(partial[base + gs])
                 + bf2f(partial[base + 2*gs]) + bf2f(partial[base + 3*gs]);
        float a1 = bf2f(partial[base + T_FIN])        + bf2f(partial[base + T_FIN + gs])
                 + bf2f(partial[base + T_FIN + 2*gs]) + bf2f(partial[base + T_FIN + 3*gs]);
        v0 = ftanh(a0 + sbc[b*256 + s0]);
        v1 = ftanh(a1 + sbc[b*256 + s0 + 1]);
      }
      unsigned u = (unsigned)f2bf(v0) | ((unsigned)f2bf(v1) << 16);
      int slot = s0 >> 3;
      *(unsigned*)(Bs + t*512 + ((slot ^ (t & 31)) << 4) + ((2*s0) & 15)) = u;
    }
  }
  __syncthreads();

  f32x4 acc[2][4] = {};
  const unsigned short* A = endWb + (size_t)(wave*32)*256;
  for (int kk = 0; kk < 8; ++kk){
    int k0 = kk*32 + q*8;
    bf16x8 a0 = *(const bf16x8*)(A + (size_t)r16*256 + k0);
    bf16x8 a1 = *(const bf16x8*)(A + (size_t)(16 + r16)*256 + k0);
    int slot = k0 >> 3;
    #pragma unroll
    for (int nt = 0; nt < 4; ++nt){
      int t = nt*16 + r16;
      bf16x8 bf = *(const bf16x8*)(Bs + t*512 + ((slot ^ (t & 31)) << 4));
      acc[0][nt] = __builtin_amdgcn_mfma_f32_16x16x32_bf16(a0, bf, acc[0][nt], 0, 0, 0);
      acc[1][nt] = __builtin_amdgcn_mfma_f32_16x16x32_bf16(a1, bf, acc[1][nt], 0, 0, 0);
    }
  }
  #pragma unroll
  for (int mt = 0; mt < 2; ++mt){
    #pragma unroll
    for (int nt = 0; nt < 4; ++nt){
      int gt = t0 + nt*16 + r16;
      if (gt < T_FIN){
        #pragma unroll
        for (int rr = 0; rr < 4; ++rr){
          int m = wave*32 + mt*16 + 4*q + rr;
          if (m < OUTC)
            out[((size_t)(b*OUTC + m))*T_FIN + gt] = fsigmoid(acc[mt][nt][rr] + end_b[m]);
        }
      }
    }
  }
}

// ---------------------------------------------------------------------------
extern "C" void kernel_launch(void* const* d_in, const int* in_sizes, int n_in,
                              void* d_out, int out_size, void* d_ws, size_t ws_size,
                              hipStream_t stream){
  const float* input     = (const float*)d_in[0];
  const float* condition = (const float*)d_in[1];
  const float* start_w   = (const float*)d_in[2];
  const float* start_b   = (const float*)d_in[3];
  const float* dil_w     = (const float*)d_in[4];
  const float* dil_b     = (const float*)d_in[5];
  const float* cond_w    = (const float*)d_in[6];
  const float* cond_b    = (const float*)d_in[7];
  const float* res_w     = (const float*)d_in[8];
  const float* res_b     = (const float*)d_in[9];
  const float* skip_w    = (const float*)d_in[10];
  const float* skip_b    = (const float*)d_in[11];
  const float* end_w     = (const float*)d_in[12];
  const float* end_b     = (const float*)d_in[13];
  const float* cend_w    = (const float*)d_in[14];
  const float* cend_b    = (const float*)d_in[15];
  float* out = (float*)d_out;

  // ws = 256 MiB (measured). Total here ~180 MiB.
  char* ws = (char*)d_ws;
  size_t off = 0;
  auto carve = [&](size_t bytes) -> char* {
    char* p = ws + off; off = (off + bytes + 255) & ~(size_t)255; return p;
  };
  unsigned short* xbA  = (unsigned short*)carve((size_t)NB*XB_T*128*2);
  unsigned short* xbB  = (unsigned short*)carve((size_t)NB*XB_T*128*2);
  unsigned short* zbuf = (unsigned short*)carve((size_t)NLAYERS*NB*ZROWS*128*2);
  unsigned short* partial = (unsigned short*)carve((size_t)NSPLIT*NB*SKIPC*T_FIN*2);
  unsigned short* dilWb   = (unsigned short*)carve((size_t)NDIL*2);
  unsigned short* skipWb  = (unsigned short*)carve((size_t)NSKP*2);
  unsigned short* resWb   = (unsigned short*)carve((size_t)NRES*2);
  unsigned short* endWb   = (unsigned short*)carve((size_t)NEND*2);
  unsigned short* startWb = (unsigned short*)carve((size_t)NSTART*2);
  float* cbias = (float*)carve((size_t)NLAYERS*NB*256*4);
  float* sbc   = (float*)carve((size_t)NB*256*4);

  prep_weights<<<2048, 256, 0, stream>>>(dil_w, skip_w, res_w, end_w, start_w,
                                         dilWb, skipWb, resWb, endWb, startWb);
  prep_bias<<<NLAYERS*NB + NB, 256, 0, stream>>>(condition, dil_b, cond_w, cond_b,
                                                 cend_w, cend_b, skip_b, cbias, sbc);

  {
    dim3 grid((T0LEN + TILE - 1)/TILE, NB);
    start_mfma<<<grid, BLK, 0, stream>>>(input, startWb, start_b, xbA);
  }

  int dils[NLAYERS]; int n = 0;
  for (int bb = 0; bb < 2; ++bb){ int nn = (bb==0) ? 10 : 9; for (int k = 0; k < nn; ++k) dils[n++] = 1<<k; }

  unsigned short* xbin = xbA; unsigned short* xbo = xbB;
  int Tin = T0LEN;
  for (int i = 0; i < NLAYERS; ++i){
    int d = dils[i]; int Tout = Tin - d;
    dim3 grid((Tout + LTILE - 1)/LTILE, NB);
    unsigned short* zlp = zbuf + (size_t)i*NB*ZROWS*128;
    layer_mfma<<<grid, BLK, 0, stream>>>(xbin, xbo, zlp, dilWb, resWb,
                                         cbias, res_b, i, d, Tin, Tout,
                                         Tout - T_FIN, (i==NLAYERS-1)?1:0);
    unsigned short* t2 = xbin; xbin = xbo; xbo = t2;
    Tin = Tout;
  }

  {
    dim3 grid((T_FIN + TILE - 1)/TILE, NB, NSPLIT);
    skipsum_mfma<<<grid, BLK, 0, stream>>>(zbuf, skipWb, partial);
  }
  {
    dim3 grid((T_FIN + TILE - 1)/TILE, NB);
    end_mfma<<<grid, BLK, 0, stream>>>(partial, endWb, sbc, end_b, out);
  }
}

// Round 20
// 478.463 us; speedup vs baseline: 1.4142x; 1.4142x over previous
//
#include <hip/hip_runtime.h>
#include <cstdint>
#include <cstddef>

#define NLAYERS 19
#define NB 4
#define RES_C 128
#define DIL2 256
#define SKIPC 256
#define INC 60
#define CONDC 80
#define OUTC 240
#define T_IN 6144
#define T0LEN 6135   // after start conv (K=10, VALID)
#define T_FIN 4601
#define TILE 64      // start/skipsum/end tile
#define LTILE 32     // layer tile
#define BLK 512
#define ZROWS 4608   // window rows per (layer,batch)
#define XB_T 6208    // xb mirror rows (T_IN + pad for tap1 overread)
#define NSPLIT 4
#define LPG 5        // layers per split group (last group has 4)

#define NDIL (NLAYERS*256*256)
#define NSKP (NLAYERS*256*128)
#define NRES (NLAYERS*128*128)
#define NEND (256*256)
#define NSTART (10*128*64)

typedef short bf16x8 __attribute__((ext_vector_type(8)));
typedef float f32x4 __attribute__((ext_vector_type(4)));
typedef unsigned uint32x2 __attribute__((ext_vector_type(2)));

#if __has_builtin(__builtin_amdgcn_exp2f)
#define EXP2F(x) __builtin_amdgcn_exp2f(x)
#else
#define EXP2F(x) exp2f(x)
#endif
#if __has_builtin(__builtin_amdgcn_rcpf)
#define RCPF(x) __builtin_amdgcn_rcpf(x)
#else
#define RCPF(x) (1.0f/(x))
#endif

__device__ __forceinline__ float fexp(float x){ return EXP2F(x * 1.4426950408889634f); }
__device__ __forceinline__ float fsigmoid(float x){ return RCPF(1.0f + fexp(-x)); }
__device__ __forceinline__ float ftanh(float x){ return 1.0f - 2.0f * RCPF(1.0f + fexp(2.0f*x)); }

__device__ __forceinline__ unsigned short f2bf(float f){
  unsigned u = __builtin_bit_cast(unsigned, f);
  u = u + 0x7FFFu + ((u >> 16) & 1u);   // RNE (finite values only)
  return (unsigned short)(u >> 16);
}
__device__ __forceinline__ float bf2f(unsigned short h){
  unsigned u = ((unsigned)h) << 16;
  return __builtin_bit_cast(float, u);
}

// async 16B global->LDS DMA; LDS dest = base + lane*16 (wave-uniform base), global src per-lane
__device__ __forceinline__ void gl_lds16(const void* g, void* l){
  __builtin_amdgcn_global_load_lds((const __attribute__((address_space(1))) unsigned int*)g,
                                   (__attribute__((address_space(3))) unsigned int*)l, 16, 0, 0);
}

// ---------------------------------------------------------------------------
// Pack weights to bf16 (R5-proven).
__global__ void prep_weights(const float* __restrict__ dil_w, const float* __restrict__ skip_w,
                             const float* __restrict__ res_w, const float* __restrict__ end_w,
                             const float* __restrict__ start_w,
                             unsigned short* __restrict__ dilWb, unsigned short* __restrict__ skipWb,
                             unsigned short* __restrict__ resWb, unsigned short* __restrict__ endWb,
                             unsigned short* __restrict__ startWb){
  const int total = NDIL + NSKP + NRES + NEND + NSTART;
  for (int idx = blockIdx.x*256 + threadIdx.x; idx < total; idx += gridDim.x*256){
    if (idx < NDIL){
      int l = idx >> 16; int rem = idx & 65535; int m = rem >> 8; int k = rem & 255;
      int o = ((m & 1) << 7) + (m >> 1); int c = k & 127; int tap = k >> 7;
      dilWb[idx] = f2bf(dil_w[(((size_t)l*256 + o)*128 + c)*2 + tap]);
    } else if (idx < NDIL + NSKP){
      int j = idx - NDIL;
      skipWb[j] = f2bf(skip_w[j]);
    } else if (idx < NDIL + NSKP + NRES){
      int j = idx - NDIL - NSKP;
      resWb[j] = f2bf(res_w[j]);
    } else if (idx < NDIL + NSKP + NRES + NEND){
      int j = idx - NDIL - NSKP - NRES;
      int m = j >> 8; int k = j & 255;
      endWb[j] = (m < OUTC) ? f2bf(end_w[(size_t)m*256 + k]) : 0;
    } else {
      int j = idx - NDIL - NSKP - NRES - NEND;
      int k = j >> 13; int rem = j & 8191; int oc = rem >> 6; int c = rem & 63;
      startWb[j] = (c < INC) ? f2bf(start_w[((size_t)oc*INC + c)*10 + k]) : 0;
    }
  }
}

// ---------------------------------------------------------------------------
__global__ void prep_bias(const float* __restrict__ cond, const float* __restrict__ dil_b,
                          const float* __restrict__ cond_w, const float* __restrict__ cond_b,
                          const float* __restrict__ cend_w, const float* __restrict__ cend_b,
                          const float* __restrict__ skip_b,
                          float* __restrict__ cbias, float* __restrict__ sbc){
  int blk = blockIdx.x; int m = threadIdx.x;
  if (blk < NLAYERS*NB){
    int l = blk >> 2, b = blk & 3;
    int o = ((m & 1) << 7) + (m >> 1);
    float acc = dil_b[l*256 + o] + cond_b[l*256 + o];
    const float* w = cond_w + ((size_t)l*256 + o)*CONDC;
    const float* cv = cond + b*CONDC;
    for (int c = 0; c < CONDC; ++c) acc += w[c]*cv[c];
    cbias[((size_t)l*NB + b)*256 + m] = acc;
  } else {
    int b = blk - NLAYERS*NB;
    float acc = cend_b[m];
    const float* w = cend_w + (size_t)m*CONDC;
    const float* cv = cond + b*CONDC;
    for (int c = 0; c < CONDC; ++c) acc += w[c]*cv[c];
    for (int l = 0; l < NLAYERS; ++l) acc += skip_b[l*256 + m];
    sbc[b*256 + m] = acc;
  }
}

// ---------------------------------------------------------------------------
// start conv via MFMA (R5-proven), writes bf16 x-mirror only
__global__ __launch_bounds__(BLK) void start_mfma(const float* __restrict__ in,
    const unsigned short* __restrict__ startWb, const float* __restrict__ bias,
    unsigned short* __restrict__ xb){
  __shared__ char Bs[80*128];   // [tt:80][c:64] bf16, slot ^= (tt&7)
  const int tid = threadIdx.x;
  const int b = blockIdx.y; const int t0 = blockIdx.x * TILE;
  const int lane = tid & 63;
  const int wave = __builtin_amdgcn_readfirstlane(tid >> 6);
  const int q = lane >> 4, r16 = lane & 15;

  #pragma unroll
  for (int i = 0; i < 5; ++i){
    int j = tid + i*BLK;              // 0..2559 = 32 c-pairs x 80 tt
    int c2 = j / 80, tt = j % 80;
    int c = 2*c2; int gt = t0 + tt;
    float v0 = 0.f, v1 = 0.f;
    if (gt < T_IN && c < INC){
      const float* base = in + ((size_t)(b*INC + c))*T_IN + gt;
      v0 = base[0]; v1 = base[T_IN];
    }
    unsigned u = (unsigned)f2bf(v0) | ((unsigned)f2bf(v1) << 16);
    int slot = c2 >> 2;
    *(unsigned*)(Bs + tt*128 + ((((slot ^ (tt & 7)) << 4)) | ((4*c2) & 15))) = u;
  }
  __syncthreads();

  f32x4 acc[4] = {};
  for (int k = 0; k < 10; ++k){
    const unsigned short* A = startWb + ((size_t)k*128 + wave*16)*64;
    #pragma unroll
    for (int kk = 0; kk < 2; ++kk){
      int k0 = kk*32 + q*8;
      bf16x8 a = *(const bf16x8*)(A + (size_t)r16*64 + k0);
      int slot = k0 >> 3;
      #pragma unroll
      for (int nt = 0; nt < 4; ++nt){
        int t = nt*16 + r16 + k;
        bf16x8 bf = *(const bf16x8*)(Bs + t*128 + ((slot ^ (t & 7)) << 4));
        acc[nt] = __builtin_amdgcn_mfma_f32_16x16x32_bf16(a, bf, acc[nt], 0, 0, 0);
      }
    }
  }
  const float* bb = bias + wave*16;
  #pragma unroll
  for (int nt = 0; nt < 4; ++nt){
    int gt = t0 + nt*16 + r16;
    if (gt < T0LEN){
      float v[4];
      #pragma unroll
      for (int rr = 0; rr < 4; ++rr) v[rr] = acc[nt][rr] + bb[4*q + rr];
      uint32x2 u;
      u.x = (unsigned)f2bf(v[0]) | ((unsigned)f2bf(v[1]) << 16);
      u.y = (unsigned)f2bf(v[2]) | ((unsigned)f2bf(v[3]) << 16);
      *(uint32x2*)(xb + ((size_t)b*XB_T + gt)*128 + wave*16 + 4*q) = u;
    }
  }
}

// ---------------------------------------------------------------------------
// Fused MFMA layer (R15-proven): bf16-only x stream. Stage via async
// global_load_lds (pre-swizzled src); dil GEMM + gate -> Bz; z-flush (LDS
// bounce, 256B rows); res GEMM with residual from BxT1; xb via LDS bounce.
__global__ __launch_bounds__(BLK) void layer_mfma(
    const unsigned short* __restrict__ xbin, unsigned short* __restrict__ xbout,
    unsigned short* __restrict__ zl,      // zbuf + l*NB*ZROWS*128
    const unsigned short* __restrict__ dilWb, const unsigned short* __restrict__ resWb,
    const float* __restrict__ cbias, const float* __restrict__ res_b,
    int layer, int d, int Tin, int Tout, int woff, int last){
  __shared__ char BxT0[LTILE*256];  // tap0 x[t]   [t][128ch] bf16, src-swizzled ^(t&15)
  __shared__ char BxT1[LTILE*256];  // tap1 x[t+d]
  __shared__ char Bz[LTILE*256];    // z [t][128ch] bf16, slot ^= (t&15)
  const int tid = threadIdx.x;
  const int b = blockIdx.y; const int t0 = blockIdx.x*LTILE;
  const int lane = tid & 63;
  const int wave = __builtin_amdgcn_readfirstlane(tid >> 6);
  const int q = lane >> 4;
  const int r16 = lane & 15;

  // ---- async stage: 2 DMA per wave (tap0, tap1), src pre-swizzled
  {
    int r = lane >> 4;               // 0..3
    int p = lane & 15;               // physical slot
    int row0 = wave*4;               // wave-uniform
    int trow = row0 + r;
    int so = (p ^ (trow & 15)) * 8;  // source element offset within row
    const unsigned short* gb = xbin + (size_t)b*XB_T*128;
    gl_lds16(gb + (size_t)(t0 + trow)*128 + so,     BxT0 + row0*256);
    gl_lds16(gb + (size_t)(t0 + trow + d)*128 + so, BxT1 + row0*256);
  }
  __syncthreads();   // drains DMA (vmcnt(0) before barrier)

  // ---- dilated GEMM: M=256 (f/g interleaved), K=256 (2 taps x 128), N=32.
  f32x4 acc[2][2] = {};
  #pragma unroll
  for (int tap = 0; tap < 2; ++tap){
    const char* Bt = tap ? BxT1 : BxT0;
    const unsigned short* A = dilWb + (size_t)layer*256*256 + (size_t)(wave*32)*256 + tap*128;
    for (int kk = 0; kk < 4; ++kk){
      int k0 = kk*32 + q*8;          // 0..127 within tap
      bf16x8 a0 = *(const bf16x8*)(A + (size_t)r16*256 + k0);
      bf16x8 a1 = *(const bf16x8*)(A + (size_t)(16 + r16)*256 + k0);
      int slot = k0 >> 3;
      #pragma unroll
      for (int nt = 0; nt < 2; ++nt){
        int t = nt*16 + r16;
        bf16x8 bf = *(const bf16x8*)(Bt + t*256 + ((slot ^ (t & 15)) << 4));
        acc[0][nt] = __builtin_amdgcn_mfma_f32_16x16x32_bf16(a0, bf, acc[0][nt], 0, 0, 0);
        acc[1][nt] = __builtin_amdgcn_mfma_f32_16x16x32_bf16(a1, bf, acc[1][nt], 0, 0, 0);
      }
    }
  }

  // ---- gate + write z to Bz (rows 4q+r hold f,g,f,g of channels 2q,2q+1)
  {
    const float* cb = cbias + ((size_t)layer*NB + b)*256 + wave*32;
    #pragma unroll
    for (int mt = 0; mt < 2; ++mt){
      float bf0 = cb[mt*16 + 4*q + 0];
      float bg0 = cb[mt*16 + 4*q + 1];
      float bf1 = cb[mt*16 + 4*q + 2];
      float bg1 = cb[mt*16 + 4*q + 3];
      int ch0 = wave*16 + mt*8 + 2*q;
      int slot = ch0 >> 3;
      #pragma unroll
      for (int nt = 0; nt < 2; ++nt){
        float z0 = ftanh(acc[mt][nt][0] + bf0) * fsigmoid(acc[mt][nt][1] + bg0);
        float z1 = ftanh(acc[mt][nt][2] + bf1) * fsigmoid(acc[mt][nt][3] + bg1);
        int t = nt*16 + r16;
        unsigned u = (unsigned)f2bf(z0) | ((unsigned)f2bf(z1) << 16);
        *(unsigned*)(Bz + t*256 + ((slot ^ (t & 15)) << 4) + ((2*ch0) & 15)) = u;
      }
    }
  }
  __syncthreads();

  // ---- z-flush: Bz -> zbuf[l][b][windex][128], coalesced rows (256B segments)
  {
    unsigned short* zgb = zl + (size_t)b*ZROWS*128;
    #pragma unroll
    for (int i = 0; i < 4; ++i){
      int j = tid + i*BLK;            // 32 rows x 64 u32
      int row = j >> 6, cu = j & 63;
      int gt = t0 + row;
      int windex = gt - woff;
      if (gt < Tout && windex >= 0){
        int slot = cu >> 2;
        unsigned u = *(const unsigned*)(Bz + row*256 + (((slot ^ (row & 15)) << 4) | ((4*cu) & 15)));
        *(unsigned*)(zgb + (size_t)windex*128 + 2*cu) = u;
      }
    }
  }

  // ---- res GEMM: M=128, K=128; residual from BxT1 (x[t+d] in LDS); bf16 out.
  if (!last){
    f32x4 racc[2] = {};
    const unsigned short* A = resWb + (size_t)layer*128*128 + (size_t)(wave*16)*128;
    for (int kk = 0; kk < 4; ++kk){
      int k0 = kk*32 + q*8;
      bf16x8 a0 = *(const bf16x8*)(A + (size_t)r16*128 + k0);
      int slot = k0 >> 3;
      #pragma unroll
      for (int nt = 0; nt < 2; ++nt){
        int t = nt*16 + r16;
        bf16x8 bf = *(const bf16x8*)(Bz + t*256 + ((slot ^ (t & 15)) << 4));
        racc[nt] = __builtin_amdgcn_mfma_f32_16x16x32_bf16(a0, bf, racc[nt], 0, 0, 0);
      }
    }
    const float* rb = res_b + layer*RES_C + wave*16;
    #pragma unroll
    for (int nt = 0; nt < 2; ++nt){
      int t = nt*16 + r16;
      float v[4];
      #pragma unroll
      for (int rr = 0; rr < 4; ++rr){
        int m = wave*16 + 4*q + rr;
        // residual: x[t+d][m] from BxT1 (same swizzle as stage wrote)
        unsigned short xh = *(const unsigned short*)(BxT1 + t*256 +
            ((((m >> 3) ^ (t & 15)) << 4) | ((2*m) & 15)));
        v[rr] = racc[nt][rr] + rb[4*q + rr] + bf2f(xh);
      }
      // pack bf16 x to LDS (reuse BxT0) for coalesced mirror write
      uint32x2 u;
      u.x = (unsigned)f2bf(v[0]) | ((unsigned)f2bf(v[1]) << 16);
      u.y = (unsigned)f2bf(v[2]) | ((unsigned)f2bf(v[3]) << 16);
      int m0 = wave*16 + 4*q;
      int slot = m0 >> 3;
      *(uint32x2*)(BxT0 + t*256 + (((slot ^ (t & 15)) << 4) | ((2*m0) & 15))) = u;
    }
    __syncthreads();
    // flush mirror rows coalesced
    unsigned short* xg = xbout + (size_t)b*XB_T*128;
    #pragma unroll
    for (int i = 0; i < 4; ++i){
      int j = tid + i*BLK;            // 32 rows x 64 u32
      int row = j >> 6, cu = j & 63;
      int gt = t0 + row;
      if (gt < Tout){
        int slot = cu >> 2;
        unsigned u = *(const unsigned*)(BxT0 + row*256 + (((slot ^ (row & 15)) << 4) | ((4*cu) & 15)));
        *(unsigned*)(xg + (size_t)gt*128 + 2*cu) = u;
      }
    }
  }
}

// ---------------------------------------------------------------------------
// pass1: partial[g] = sum_{l in group g} skipW[l] @ z_l  (bf16, window-aligned)
__global__ __launch_bounds__(BLK) void skipsum_mfma(
    const unsigned short* __restrict__ zbuf,
    const unsigned short* __restrict__ skipWb,
    unsigned short* __restrict__ partial){
  __shared__ char BzP[2][64*256];   // z tile double-buffer, slot ^= (row&15)
  const int tid = threadIdx.x;
  const int b = blockIdx.y; const int t0 = blockIdx.x*TILE;
  const int g = blockIdx.z;
  const int l0 = g*LPG;
  const int l1 = (l0 + LPG < NLAYERS) ? (l0 + LPG) : NLAYERS;
  const int lane = tid & 63;
  const int wave = __builtin_amdgcn_readfirstlane(tid >> 6);
  const int q = lane >> 4, r16 = lane & 15;

  auto stageZ = [&](int l, int buf){
    int r = lane >> 4, p = lane & 15;
    const unsigned short* zb = zbuf + ((size_t)l*NB + b)*ZROWS*128;
    #pragma unroll
    for (int h = 0; h < 2; ++h){
      int row0 = wave*8 + h*4;       // wave-uniform
      int trow = row0 + r;
      gl_lds16(zb + (size_t)(t0 + trow)*128 + (p ^ (trow & 15))*8,
               BzP[buf] + row0*256);
    }
  };

  stageZ(l0, l0 & 1);
  __syncthreads();

  f32x4 sacc[2][4] = {};
  for (int l = l0; l < l1; ++l){
    if (l + 1 < l1) stageZ(l + 1, (l + 1) & 1);
    const unsigned short* A = skipWb + ((size_t)l*256 + wave*32)*128;
    const char* Bb = BzP[l & 1];
    for (int kk = 0; kk < 4; ++kk){
      int k0 = kk*32 + q*8;
      bf16x8 a0 = *(const bf16x8*)(A + (size_t)r16*128 + k0);
      bf16x8 a1 = *(const bf16x8*)(A + (size_t)(16 + r16)*128 + k0);
      int slot = k0 >> 3;
      #pragma unroll
      for (int nt = 0; nt < 4; ++nt){
        int t = nt*16 + r16;
        bf16x8 bf = *(const bf16x8*)(Bb + t*256 + ((slot ^ (t & 15)) << 4));
        sacc[0][nt] = __builtin_amdgcn_mfma_f32_16x16x32_bf16(a0, bf, sacc[0][nt], 0, 0, 0);
        sacc[1][nt] = __builtin_amdgcn_mfma_f32_16x16x32_bf16(a1, bf, sacc[1][nt], 0, 0, 0);
      }
    }
    __syncthreads();
  }

  unsigned short* pg = partial + (size_t)g*NB*SKIPC*T_FIN;
  #pragma unroll
  for (int mt = 0; mt < 2; ++mt){
    #pragma unroll
    for (int nt = 0; nt < 4; ++nt){
      int gt = t0 + nt*16 + r16;
      if (gt < T_FIN){
        #pragma unroll
        for (int rr = 0; rr < 4; ++rr){
          int m = wave*32 + mt*16 + 4*q + rr;
          pg[((size_t)(b*SKIPC + m))*T_FIN + gt] = f2bf(sacc[mt][nt][rr]);
        }
      }
    }
  }
}

// ---------------------------------------------------------------------------
// pass2: out = sigmoid(end_b + endW @ tanh(sum_g partial[g] + sbc))
__global__ __launch_bounds__(BLK) void end_mfma(
    const unsigned short* __restrict__ partial, const unsigned short* __restrict__ endWb,
    const float* __restrict__ sbc, const float* __restrict__ end_b,
    float* __restrict__ out){
  __shared__ char Bs[64*512];   // [t][s:256] bf16, slot ^= (t&31)
  const int tid = threadIdx.x;
  const int b = blockIdx.y; const int t0 = blockIdx.x*TILE;
  const int lane = tid & 63;
  const int wave = __builtin_amdgcn_readfirstlane(tid >> 6);
  const int q = lane >> 4;
  const int r16 = lane & 15;
  const size_t gs = (size_t)NB*SKIPC*T_FIN;

  {
    const int t = lane;
    const int gt = t0 + t;
    #pragma unroll
    for (int i = 0; i < 32; i += 2){
      int s0 = wave*32 + i;
      float v0 = 0.f, v1 = 0.f;
      if (gt < T_FIN){
        size_t base = ((size_t)(b*SKIPC + s0))*T_FIN + gt;
        float a0 = bf2f(partial[base])        + bf2f(partial[base + gs])
                 + bf2f(partial[base + 2*gs]) + bf2f(partial[base + 3*gs]);
        float a1 = bf2f(partial[base + T_FIN])        + bf2f(partial[base + T_FIN + gs])
                 + bf2f(partial[base + T_FIN + 2*gs]) + bf2f(partial[base + T_FIN + 3*gs]);
        v0 = ftanh(a0 + sbc[b*256 + s0]);
        v1 = ftanh(a1 + sbc[b*256 + s0 + 1]);
      }
      unsigned u = (unsigned)f2bf(v0) | ((unsigned)f2bf(v1) << 16);
      int slot = s0 >> 3;
      *(unsigned*)(Bs + t*512 + ((slot ^ (t & 31)) << 4) + ((2*s0) & 15)) = u;
    }
  }
  __syncthreads();

  f32x4 acc[2][4] = {};
  const unsigned short* A = endWb + (size_t)(wave*32)*256;
  for (int kk = 0; kk < 8; ++kk){
    int k0 = kk*32 + q*8;
    bf16x8 a0 = *(const bf16x8*)(A + (size_t)r16*256 + k0);
    bf16x8 a1 = *(const bf16x8*)(A + (size_t)(16 + r16)*256 + k0);
    int slot = k0 >> 3;
    #pragma unroll
    for (int nt = 0; nt < 4; ++nt){
      int t = nt*16 + r16;
      bf16x8 bf = *(const bf16x8*)(Bs + t*512 + ((slot ^ (t & 31)) << 4));
      acc[0][nt] = __builtin_amdgcn_mfma_f32_16x16x32_bf16(a0, bf, acc[0][nt], 0, 0, 0);
      acc[1][nt] = __builtin_amdgcn_mfma_f32_16x16x32_bf16(a1, bf, acc[1][nt], 0, 0, 0);
    }
  }
  #pragma unroll
  for (int mt = 0; mt < 2; ++mt){
    #pragma unroll
    for (int nt = 0; nt < 4; ++nt){
      int gt = t0 + nt*16 + r16;
      if (gt < T_FIN){
        #pragma unroll
        for (int rr = 0; rr < 4; ++rr){
          int m = wave*32 + mt*16 + 4*q + rr;
          if (m < OUTC)
            out[((size_t)(b*OUTC + m))*T_FIN + gt] = fsigmoid(acc[mt][nt][rr] + end_b[m]);
        }
      }
    }
  }
}

// ---------------------------------------------------------------------------
extern "C" void kernel_launch(void* const* d_in, const int* in_sizes, int n_in,
                              void* d_out, int out_size, void* d_ws, size_t ws_size,
                              hipStream_t stream){
  const float* input     = (const float*)d_in[0];
  const float* condition = (const float*)d_in[1];
  const float* start_w   = (const float*)d_in[2];
  const float* start_b   = (const float*)d_in[3];
  const float* dil_w     = (const float*)d_in[4];
  const float* dil_b     = (const float*)d_in[5];
  const float* cond_w    = (const float*)d_in[6];
  const float* cond_b    = (const float*)d_in[7];
  const float* res_w     = (const float*)d_in[8];
  const float* res_b     = (const float*)d_in[9];
  const float* skip_w    = (const float*)d_in[10];
  const float* skip_b    = (const float*)d_in[11];
  const float* end_w     = (const float*)d_in[12];
  const float* end_b     = (const float*)d_in[13];
  const float* cend_w    = (const float*)d_in[14];
  const float* cend_b    = (const float*)d_in[15];
  float* out = (float*)d_out;

  // ws = 256 MiB (measured). Total here ~180 MiB.
  char* ws = (char*)d_ws;
  size_t off = 0;
  auto carve = [&](size_t bytes) -> char* {
    char* p = ws + off; off = (off + bytes + 255) & ~(size_t)255; return p;
  };
  unsigned short* xbA  = (unsigned short*)carve((size_t)NB*XB_T*128*2);
  unsigned short* xbB  = (unsigned short*)carve((size_t)NB*XB_T*128*2);
  unsigned short* zbuf = (unsigned short*)carve((size_t)NLAYERS*NB*ZROWS*128*2);
  unsigned short* partial = (unsigned short*)carve((size_t)NSPLIT*NB*SKIPC*T_FIN*2);
  unsigned short* dilWb   = (unsigned short*)carve((size_t)NDIL*2);
  unsigned short* skipWb  = (unsigned short*)carve((size_t)NSKP*2);
  unsigned short* resWb   = (unsigned short*)carve((size_t)NRES*2);
  unsigned short* endWb   = (unsigned short*)carve((size_t)NEND*2);
  unsigned short* startWb = (unsigned short*)carve((size_t)NSTART*2);
  float* cbias = (float*)carve((size_t)NLAYERS*NB*256*4);
  float* sbc   = (float*)carve((size_t)NB*256*4);

  prep_weights<<<2048, 256, 0, stream>>>(dil_w, skip_w, res_w, end_w, start_w,
                                         dilWb, skipWb, resWb, endWb, startWb);
  prep_bias<<<NLAYERS*NB + NB, 256, 0, stream>>>(condition, dil_b, cond_w, cond_b,
                                                 cend_w, cend_b, skip_b, cbias, sbc);

  {
    dim3 grid((T0LEN + TILE - 1)/TILE, NB);
    start_mfma<<<grid, BLK, 0, stream>>>(input, startWb, start_b, xbA);
  }

  int dils[NLAYERS]; int n = 0;
  for (int bb = 0; bb < 2; ++bb){ int nn = (bb==0) ? 10 : 9; for (int k = 0; k < nn; ++k) dils[n++] = 1<<k; }

  unsigned short* xbin = xbA; unsigned short* xbo = xbB;
  int Tin = T0LEN;
  for (int i = 0; i < NLAYERS; ++i){
    int d = dils[i]; int Tout = Tin - d;
    dim3 grid((Tout + LTILE - 1)/LTILE, NB);
    unsigned short* zlp = zbuf + (size_t)i*NB*ZROWS*128;
    layer_mfma<<<grid, BLK, 0, stream>>>(xbin, xbo, zlp, dilWb, resWb,
                                         cbias, res_b, i, d, Tin, Tout,
                                         Tout - T_FIN, (i==NLAYERS-1)?1:0);
    unsigned short* t2 = xbin; xbin = xbo; xbo = t2;
    Tin = Tout;
  }

  {
    dim3 grid((T_FIN + TILE - 1)/TILE, NB, NSPLIT);
    skipsum_mfma<<<grid, BLK, 0, stream>>>(zbuf, skipWb, partial);
  }
  {
    dim3 grid((T_FIN + TILE - 1)/TILE, NB);
    end_mfma<<<grid, BLK, 0, stream>>>(partial, endWb, sbc, end_b, out);
  }
}